// Round 4
// baseline (906.685 us; speedup 1.0000x reference)
//
#include <hip/hip_runtime.h>

// ---------------------------------------------------------------------------
// SelfAttentionModule: q/k/v proj + relative_key_query attention, MI355X.
// B=4, S=1024, D=1024, H=16, HD=64, MAXPOS=1024.
//
// Round-4 core change (k_attn): kill the per-iteration HBM-latency drain.
//  - manual VGPR->LDS staging (precise compiler vmcnt tracking, no LDS-DMA
//    coarse drain)
//  - raw `s_waitcnt lgkmcnt(0); s_barrier` barriers (LDS-only hazards) so
//    global loads stay in flight across barriers
//  - prior/mask prefetched ONE ITERATION ahead into registers, issued after
//    the staging loads (FIFO vmcnt: waiting for staging leaves prior flying)
// ---------------------------------------------------------------------------

typedef unsigned short u16;
typedef unsigned int   u32;
typedef unsigned long long u64;
typedef __attribute__((ext_vector_type(8))) short bfx8;   // 8 bf16 = 4 VGPR
typedef __attribute__((ext_vector_type(4))) float f32x4;  // MFMA C/D

#define MFMA_BF16(a, b, c) __builtin_amdgcn_mfma_f32_16x16x32_bf16(a, b, c, 0, 0, 0)

// raw barrier: LDS-visibility only; does NOT drain vmcnt (that's the point)
#define BAR_LDS() asm volatile("s_waitcnt lgkmcnt(0)\n\ts_barrier" ::: "memory")
#define CFENCE()  asm volatile("" ::: "memory")

__device__ __forceinline__ u16 f2bf(float f) {
    union { float f; u32 u; } c; c.f = f;
    u32 u = c.u;
    return (u16)((u + 0x7FFFu + ((u >> 16) & 1u)) >> 16);  // RNE
}
__device__ __forceinline__ float bf2f(u16 v) {
    union { u32 u; float f; } c; c.u = ((u32)v) << 16;
    return c.f;
}
__device__ __forceinline__ float load_f(const void* p, long i, bool bf) {
    return bf ? bf2f(((const u16*)p)[i]) : ((const float*)p)[i];
}
__device__ __forceinline__ u16 load_bf(const void* p, long i, bool bf) {
    return bf ? ((const u16*)p)[i] : f2bf(((const float*)p)[i]);
}

// async global->LDS (still used by the GEMM, whose loop is long enough)
__device__ __forceinline__ void gload16(const u16* g, u16* l) {
    __builtin_amdgcn_global_load_lds(
        (__attribute__((address_space(1))) void*)g,
        (__attribute__((address_space(3))) void*)l, 16, 0, 0);
}

// ---------------------------------------------------------------------------
__global__ void k_detect(const u32* hid, int* flags) {
    __shared__ int cnt;
    if (threadIdx.x == 0) cnt = 0;
    __syncthreads();
    int c = 0;
    for (int i = threadIdx.x; i < 1024; i += 256) {
        u32 w = hid[i];
        u32 e = (w >> 7) & 0xFFu;
        if (e >= 100u && e <= 140u) c++;
    }
    atomicAdd(&cnt, c);
    __syncthreads();
    if (threadIdx.x == 0) flags[0] = (cnt > 512) ? 1 : 0;
}

// ---------------------------------------------------------------------------
// vectorized prep: hidden/dist as 4-element units, tiny scalar tail
__global__ void k_prep(const void* hidden, const void* dist, const void* mask,
                       const void* hm, const void* bq, const void* bk,
                       const void* bv, const int* flags, u16* hid_bf,
                       u16* dist_bf, float* mask_f, float* hm_f, float* bias_f) {
    const bool bf = flags[0] != 0;
    const long VH = 1048576, VD = 32752;   // 4M/4, 131008/4
    const long SC = 4096 + 3072 + 16;
    const long TOT = VH + VD + SC;
    for (long i = (long)blockIdx.x * 256 + threadIdx.x; i < TOT;
         i += (long)gridDim.x * 256) {
        if (i < VH + VD) {
            const void* src = (i < VH) ? hidden : dist;
            u16* dst = (i < VH) ? hid_bf : dist_bf;
            long j = (i < VH) ? i : i - VH;
            if (bf) {
                ((int2*)dst)[j] = ((const int2*)src)[j];
            } else {
                float4 v = ((const float4*)src)[j];
                ushort4 o;
                o.x = f2bf(v.x); o.y = f2bf(v.y);
                o.z = f2bf(v.z); o.w = f2bf(v.w);
                ((ushort4*)dst)[j] = o;
            }
        } else {
            long j = i - VH - VD;
            if (j < 4096) mask_f[j] = load_f(mask, j, bf);
            else if (j < 7168) {
                long k = j - 4096;
                const void* src = (k < 1024) ? bq : ((k < 2048) ? bk : bv);
                bias_f[k] = load_f(src, k & 1023, bf);
            } else hm_f[j - 7168] = load_f(hm, j - 7168, bf);
        }
    }
}

// W[k][n] -> Wt[n][k] (bf16). grid (32,32,3), block (32,8)
__global__ void k_transpose(const void* Wq, const void* Wk, const void* Wv,
                            const int* flags, u16* wt) {
    const bool bf = flags[0] != 0;
    __shared__ float t[32][33];
    const int z = blockIdx.z;
    const void* W = (z == 0) ? Wq : ((z == 1) ? Wk : Wv);
    int x = blockIdx.x * 32 + threadIdx.x;  // n
    for (int i = 0; i < 4; i++) {
        int y = blockIdx.y * 32 + threadIdx.y + i * 8;  // k
        t[threadIdx.y + i * 8][threadIdx.x] = load_f(W, (long)y * 1024 + x, bf);
    }
    __syncthreads();
    int x2 = blockIdx.y * 32 + threadIdx.x;  // k
    u16* out = wt + (long)z * 1024 * 1024;
    for (int i = 0; i < 4; i++) {
        int y2 = blockIdx.x * 32 + threadIdx.y + i * 8;  // n
        out[(long)y2 * 1024 + x2] = f2bf(t[threadIdx.x][threadIdx.y + i * 8]);
    }
}

// ---------------------------------------------------------------------------
// QKV GEMM: C[m,n] = sum_k A[m,k]*Wt[n,k] + bias[n]; M=4096, N=3072, K=1024.
__global__ __launch_bounds__(256, 2)
void k_qkv_gemm(const u16* A, const u16* Bt, const float* bias,
                u16* qb, u16* kb, u16* vb) {
    __shared__ u16 sA[128 * 32];  // unpadded: required by global_load_lds
    __shared__ u16 sB[128 * 32];
    const int tid = threadIdx.x;
    const int w = tid >> 6, lane = tid & 63;
    const int quad = lane >> 4, nl = lane & 15;
    const int wr = w >> 1, wc = w & 1;
    const int n0 = blockIdx.x * 128, m0 = blockIdx.y * 128;

    f32x4 acc[4][4];
#pragma unroll
    for (int a = 0; a < 4; a++)
#pragma unroll
        for (int b = 0; b < 4; b++) acc[a][b] = (f32x4){0.f, 0.f, 0.f, 0.f};

    for (int kt = 0; kt < 32; kt++) {
        const int k0 = kt * 32;
        __syncthreads();
#pragma unroll
        for (int j = 0; j < 2; j++) {
            int row = 32 * w + 16 * j + (lane >> 2);
            int seg = lane & 3;
            gload16(A + (long)(m0 + row) * 1024 + k0 + seg * 8, sA + 1024 * w + 512 * j);
            gload16(Bt + (long)(n0 + row) * 1024 + k0 + seg * 8, sB + 1024 * w + 512 * j);
        }
        __syncthreads();

        bfx8 af[4], bfr[4];
#pragma unroll
        for (int f = 0; f < 4; f++) {
            af[f]  = *(const bfx8*)(sA + (64 * wr + 16 * f + nl) * 32 + quad * 8);
            bfr[f] = *(const bfx8*)(sB + (64 * wc + 16 * f + nl) * 32 + quad * 8);
        }
#pragma unroll
        for (int fm = 0; fm < 4; fm++)
#pragma unroll
            for (int fn = 0; fn < 4; fn++)
                acc[fm][fn] = MFMA_BF16(af[fm], bfr[fn], acc[fm][fn]);
    }

    // epilogue: +bias; q,k -> [bh][s][64]; v -> TRANSPOSED [bh][64][s]
#pragma unroll
    for (int fm = 0; fm < 4; fm++) {
#pragma unroll
        for (int fn = 0; fn < 4; fn++) {
            int n = n0 + 64 * wc + 16 * fn + nl;
            int which = n >> 10, hcol = n & 1023;
            int h = hcol >> 6, hd = hcol & 63;
            float bias_v = bias[n];
            int mbase = m0 + 64 * wr + 16 * fm + 4 * quad;
            int b = mbase >> 10, s = mbase & 1023;
            if (which == 2) {
                u64 pk = 0;
#pragma unroll
                for (int reg = 0; reg < 4; reg++)
                    pk |= (u64)f2bf(acc[fm][fn][reg] + bias_v) << (16 * reg);
                *(u64*)&vb[((long)((b * 16 + h) * 64 + hd)) * 1024 + s] = pk;
            } else {
                u16* op = (which == 0) ? qb : kb;
#pragma unroll
                for (int reg = 0; reg < 4; reg++)
                    op[((long)((b * 16 + h) * 1024 + s + reg)) * 64 + hd] =
                        f2bf(acc[fm][fn][reg] + bias_v);
            }
        }
    }
}

// ---------------------------------------------------------------------------
// Fused attention. grid (B*H=64, S/64=16), 256 threads = 4 waves.
// Wave w owns score rows 16w..16w+15 of the 64-row l-tile.
// Bias boards (shifted-diagonal storage, R3 algebra):
//   board_q[l][t] = q[l].pe(u=l+t),  t = 63-r   (producer window fc in [w,w+4])
//   board_k[l][r] = k[r].pe(u=l-r+63)           (producer window fc in [3-w,7-w])
__global__ __launch_bounds__(256, 3)
void k_attn(const u16* qb, const u16* kb, const u16* vTb, const u16* Eb,
            const float* maskf, const float* hmf, const void* prior,
            const int* flags, void* out) {
    __shared__ __align__(16) u16 smem[27136];  // 54272 B -> 3 blocks/CU
    u16* sK  = smem;            // [64 r][72]   padded pitch, b128-friendly
    u16* sVT = smem + 4608;     // [64 d][72]
    u16* sE  = smem + 9216;     // [128 u][72]
    u16* sP  = smem + 9216;     // [64 l][72]   alias sE (dead after band)
    u16* bqB = smem + 18432;    // [64 l][68 t]
    u16* bkB = smem + 22784;    // [64 l][68 r]

    const int tid = threadIdx.x;
    const int w = tid >> 6, lane = tid & 63;
    const int quad = lane >> 4, nl = lane & 15;
    const int bh = blockIdx.x, b = bh >> 4, h = bh & 15;
    const int l0 = blockIdx.y * 64;
    const bool bf = flags[0] != 0;

    const u16* qbh = qb  + (long)bh * 65536;
    const u16* kbh = kb  + (long)bh * 65536;
    const u16* vbh = vTb + (long)bh * 65536;   // [64 d][1024 s]

    // Q A-frags once, direct from global
    const bfx8 aq0 = *(const bfx8*)(qbh + (l0 + 16 * w + nl) * 64 + quad * 8);
    const bfx8 aq1 = *(const bfx8*)(qbh + (l0 + 16 * w + nl) * 64 + quad * 8 + 32);

    f32x4 accv[4];
#pragma unroll
    for (int f = 0; f < 4; f++) accv[f] = (f32x4){0.f, 0.f, 0.f, 0.f};
    float zacc[4] = {0.f, 0.f, 0.f, 0.f};
    const int jb_base = l0 + 960;

    const int lpb  = 16 * w + 4 * quad;
    const int bqrd = lpb * 68 + 63 - nl;
    const int bkrd = lpb * 68 + nl;

    // prior/mask prefetch (one iteration ahead). prologue: iter-0 values.
    float pr_c[4][4], mv_c[4], pr_n[4][4], mv_n[4];
#pragma unroll
    for (int fn = 0; fn < 4; fn++) {
        mv_c[fn] = maskf[b * 1024 + fn * 16 + nl];
#pragma unroll
        for (int reg = 0; reg < 4; reg++) {
            long pidx = ((long)(bh * 1024 + l0 + lpb + reg)) * 1024 + fn * 16 + nl;
            pr_c[fn][reg] = bf ? bf2f(((const u16*)prior)[pidx])
                               : ((const float*)prior)[pidx];
        }
    }

#pragma unroll 2
    for (int it = 0; it < 16; it++) {
        const int r0 = it * 64;
        BAR_LDS();  // (A) prev-iter LDS consumers done before restage

        // ---- staging loads (oldest in vmcnt FIFO)
        int4 vKr[2], vVr[2], vEr[4];
#pragma unroll
        for (int p = 0; p < 2; p++) {
            int cid = tid + 256 * p, row = cid >> 3, c8 = cid & 7;
            vKr[p] = *(const int4*)(kbh + (r0 + row) * 64 + c8 * 8);
            vVr[p] = *(const int4*)(vbh + row * 1024 + r0 + c8 * 8);
        }
        const int jb = jb_base - r0;
#pragma unroll
        for (int p = 0; p < 4; p++) {
            int cid = tid + 256 * p, row = cid >> 3, c8 = cid & 7;
            int je = jb + row;
            je = je < 0 ? 0 : (je > 2046 ? 2046 : je);  // clamped rows feed
            vEr[p] = *(const int4*)(Eb + je * 64 + c8 * 8);  // masked lanes only
        }
        CFENCE();
        // ---- prefetch NEXT iter's prior/mask (stays in flight across
        //      barriers; consumed next iteration -> latency fully hidden)
        {
            const int itn = it < 15 ? it + 1 : it;
            const int r0n = itn * 64;
#pragma unroll
            for (int fn = 0; fn < 4; fn++) {
                mv_n[fn] = maskf[b * 1024 + r0n + fn * 16 + nl];
#pragma unroll
                for (int reg = 0; reg < 4; reg++) {
                    long pidx = ((long)(bh * 1024 + l0 + lpb + reg)) * 1024
                                + r0n + fn * 16 + nl;
                    pr_n[fn][reg] = bf ? bf2f(((const u16*)prior)[pidx])
                                       : ((const float*)prior)[pidx];
                }
            }
        }
        CFENCE();
        // ---- LDS writes (compiler waits vmcnt only for staging regs)
#pragma unroll
        for (int p = 0; p < 2; p++) {
            int cid = tid + 256 * p, row = cid >> 3, c8 = cid & 7;
            *(int4*)(sK  + row * 72 + c8 * 8) = vKr[p];
            *(int4*)(sVT + row * 72 + c8 * 8) = vVr[p];
        }
#pragma unroll
        for (int p = 0; p < 4; p++) {
            int cid = tid + 256 * p, row = cid >> 3, c8 = cid & 7;
            *(int4*)(sE + row * 72 + c8 * 8) = vEr[p];
        }
        BAR_LDS();  // (B) staged tiles visible

        // ---- band GEMMs (live windows only) -> bias boards
        const bfx8 ak0 = *(const bfx8*)(sK + (16 * w + nl) * 72 + quad * 8);
        const bfx8 ak1 = *(const bfx8*)(sK + (16 * w + nl) * 72 + quad * 8 + 32);
#pragma unroll
        for (int d = 0; d < 5; d++) {
            const int fc = w + d;  // Dq live window [w, w+4]
            bfx8 be0 = *(const bfx8*)(sE + (fc * 16 + nl) * 72 + quad * 8);
            bfx8 be1 = *(const bfx8*)(sE + (fc * 16 + nl) * 72 + quad * 8 + 32);
            f32x4 dq = (f32x4){0.f, 0.f, 0.f, 0.f};
            dq = MFMA_BF16(aq0, be0, dq);
            dq = MFMA_BF16(aq1, be1, dq);
#pragma unroll
            for (int reg = 0; reg < 4; reg++) {
                int lp = lpb + reg;
                int t = 16 * fc + nl - lp;
                if (t >= 0 && t < 64) bqB[lp * 68 + t] = f2bf(dq[reg]);
            }
        }
#pragma unroll
        for (int d = 0; d < 5; d++) {
            const int fc = 3 - w + d;  // Dk live window [3-w, 7-w]
            bfx8 be0 = *(const bfx8*)(sE + (fc * 16 + nl) * 72 + quad * 8);
            bfx8 be1 = *(const bfx8*)(sE + (fc * 16 + nl) * 72 + quad * 8 + 32);
            f32x4 dk = (f32x4){0.f, 0.f, 0.f, 0.f};
            dk = MFMA_BF16(ak0, be0, dk);
            dk = MFMA_BF16(ak1, be1, dk);
#pragma unroll
            for (int reg = 0; reg < 4; reg++) {
                int rp = lpb + reg;
                int row = 16 * fc + nl + rp - 63;
                if (row >= 0 && row < 64) bkB[row * 68 + rp] = f2bf(dk[reg]);
            }
        }
        // ---- QK^T for this wave's 16 rows x 64 cols
        f32x4 accs[4];
#pragma unroll
        for (int fn = 0; fn < 4; fn++) {
            bfx8 bk0 = *(const bfx8*)(sK + (fn * 16 + nl) * 72 + quad * 8);
            bfx8 bk1 = *(const bfx8*)(sK + (fn * 16 + nl) * 72 + quad * 8 + 32);
            f32x4 s = (f32x4){0.f, 0.f, 0.f, 0.f};
            s = MFMA_BF16(aq0, bk0, s);
            s = MFMA_BF16(aq1, bk1, s);
            accs[fn] = s;
        }
        BAR_LDS();  // (C) boards visible; sE dead -> sP region free

        // ---- combine: 2 linear b16 reads/elem, exp, prior, sP write
#pragma unroll
        for (int fn = 0; fn < 4; fn++) {
#pragma unroll
            for (int reg = 0; reg < 4; reg++) {
                float dqv = bf2f(bqB[bqrd + reg * 68 - fn * 16]);
                float dkv = bf2f(bkB[bkrd + reg * 68 + fn * 16]);
                float s = (accs[fn][reg] + dqv + dkv) * 0.125f + mv_c[fn];
                float e = __expf(s);   // logits ~ +-3: no max pass needed
                zacc[reg] += e;
                sP[(lpb + reg) * 72 + fn * 16 + nl] = f2bf(e * pr_c[fn][reg]);
            }
        }
        // sP rows 16w.. written and read by the SAME wave: lgkm wait only
        bfx8 ap0 = *(const bfx8*)(sP + (16 * w + nl) * 72 + quad * 8);
        bfx8 ap1 = *(const bfx8*)(sP + (16 * w + nl) * 72 + quad * 8 + 32);
#pragma unroll
        for (int fd = 0; fd < 4; fd++) {
            bfx8 bv0 = *(const bfx8*)(sVT + (fd * 16 + nl) * 72 + quad * 8);
            bfx8 bv1 = *(const bfx8*)(sVT + (fd * 16 + nl) * 72 + quad * 8 + 32);
            accv[fd] = MFMA_BF16(ap0, bv0, accv[fd]);
            accv[fd] = MFMA_BF16(ap1, bv1, accv[fd]);
        }
        // ---- rotate prior double-buffer (renamed away by unroll 2)
#pragma unroll
        for (int fn = 0; fn < 4; fn++) {
            mv_c[fn] = mv_n[fn];
#pragma unroll
            for (int reg = 0; reg < 4; reg++) pr_c[fn][reg] = pr_n[fn][reg];
        }
    }

    // ---- finalize: reduce Z over the 16 col-lanes, scale, store
#pragma unroll
    for (int reg = 0; reg < 4; reg++) {
        float z = zacc[reg];
        z += __shfl_xor(z, 1);
        z += __shfl_xor(z, 2);
        z += __shfl_xor(z, 4);
        z += __shfl_xor(z, 8);
        zacc[reg] = z;
    }
    const float hm = hmf[h];
#pragma unroll
    for (int fd = 0; fd < 4; fd++) {
#pragma unroll
        for (int reg = 0; reg < 4; reg++) {
            int l = l0 + 16 * w + 4 * quad + reg;
            int d = fd * 16 + nl;
            float val = accv[fd][reg] * hm / zacc[reg];
            long oidx = ((long)(b * 1024 + l)) * 1024 + h * 64 + d;
            if (bf) ((u16*)out)[oidx] = f2bf(val);
            else    ((float*)out)[oidx] = val;
        }
    }
}

// ---------------------------------------------------------------------------
extern "C" void kernel_launch(void* const* d_in, const int* in_sizes, int n_in,
                              void* d_out, int out_size, void* d_ws, size_t ws_size,
                              hipStream_t stream) {
    // d_in: 0 hidden, 1 attention_mask, 2 prior, 3 head_mask,
    //       4 Wq, 5 bq, 6 Wk, 7 bk, 8 Wv, 9 bv, 10 dist_emb
    char* ws = (char*)d_ws;
    int*   flags   = (int*)ws;                  //       16 B (256 reserved)
    u16*   hid_bf  = (u16*)(ws + 256);          //  8388608 B
    u16*   wt_bf   = (u16*)(ws + 8388864);      //  6291456 B
    u16*   dist_bf = (u16*)(ws + 14680320);     //   262144 B
    float* mask_f  = (float*)(ws + 14942464);   //    16384 B
    float* bias_f  = (float*)(ws + 14958848);   //    12288 B
    float* hm_f    = (float*)(ws + 14971136);   //      256 B
    u16*   q_bf    = (u16*)(ws + 14971392);     //  8388608 B  [bh][s][d]
    u16*   k_bf    = (u16*)(ws + 23360000);     //  8388608 B  [bh][s][d]
    u16*   v_bf    = (u16*)(ws + 31748608);     //  8388608 B  [bh][d][s] (T)

    k_detect<<<1, 256, 0, stream>>>((const u32*)d_in[0], flags);
    k_prep<<<1024, 256, 0, stream>>>(d_in[0], d_in[10], d_in[1], d_in[3],
                                     d_in[5], d_in[7], d_in[9], flags,
                                     hid_bf, dist_bf, mask_f, hm_f, bias_f);
    k_transpose<<<dim3(32, 32, 3), dim3(32, 8), 0, stream>>>(
        d_in[4], d_in[6], d_in[8], flags, wt_bf);
    k_qkv_gemm<<<dim3(24, 32), 256, 0, stream>>>(hid_bf, wt_bf, bias_f,
                                                 q_bf, k_bf, v_bf);
    k_attn<<<dim3(64, 16), 256, 0, stream>>>(q_bf, k_bf, v_bf, dist_bf,
                                             mask_f, hm_f, d_in[2], flags, d_out);
}